// Round 3
// baseline (288.517 us; speedup 1.0000x reference)
//
#include <hip/hip_runtime.h>
#include <stdint.h>

// PointPillars constants (KITTI config)
#define GRID_X 432
#define GRID_Y 496
#define NB 4
#define NPTS 32
#define NC 64
#define NSLOTS 64
#define CELLS (GRID_Y * GRID_X)   // 214272 per batch (y-major, x fastest)
#define QCELLS (CELLS / 4)        // 53568 float4 quads per (b, channel) plane

constexpr float VXc = 0.16f, VYc = 0.16f;
constexpr float X_OFFSET = 0.08f, Y_OFFSET = -39.60f, Z_CONST = -1.0f;
constexpr float BN_EPS = 1e-3f;

typedef float floatx4 __attribute__((ext_vector_type(4)));  // native vec for nontemporal

#define PPB 16   // pillars per block in stats kernel

// Kernel A: per-pillar feature max/min per channel + BN stat partials + inverse map
__global__ __launch_bounds__(256) void pillar_stats_kernel(
    const float* __restrict__ pillars, const float* __restrict__ W,
    const int* __restrict__ cx, const int* __restrict__ cy,
    const int* __restrict__ cb, const int* __restrict__ npoints,
    float* __restrict__ vmax, float* __restrict__ vmin, int* __restrict__ map,
    double* __restrict__ dsum, double* __restrict__ dsq, int P)
{
    __shared__ float4 pts[PPB][NPTS];    // 8 KB
    __shared__ float pinfo[PPB][4];      // mx, my, mz, npf
    __shared__ float ssum[4][NC], ssq[4][NC];

    const int tid = threadIdx.x;
    const int p0 = blockIdx.x * PPB;

    // Phase A: stage points + per-pillar xyz centroid (8 pillars per pass, 2 passes)
    #pragma unroll
    for (int pass = 0; pass < 2; ++pass) {
        int pl = (tid >> 5) + pass * 8;
        int n  = tid & 31;
        int p  = p0 + pl;
        float4 v = make_float4(0.f, 0.f, 0.f, 0.f);
        if (p < P) v = ((const float4*)pillars)[(size_t)p * NPTS + n];
        pts[pl][n] = v;
        float sx = v.x, sy = v.y, sz = v.z;
        #pragma unroll
        for (int m = 16; m >= 1; m >>= 1) {
            sx += __shfl_xor(sx, m, 32);
            sy += __shfl_xor(sy, m, 32);
            sz += __shfl_xor(sz, m, 32);
        }
        if (n == 0 && p < P) {
            float npf = (float)npoints[p];
            pinfo[pl][0] = sx / npf;
            pinfo[pl][1] = sy / npf;
            pinfo[pl][2] = sz / npf;
            pinfo[pl][3] = npf;
        }
    }
    // inverse map: cell -> pillar index (cells unique per batch by construction)
    if (tid < PPB) {
        int p = p0 + tid;
        if (p < P) {
            int b = cb[p];
            map[(size_t)b * CELLS + (size_t)cy[p] * GRID_X + cx[p]] = p;
        }
    }
    __syncthreads();

    // Phase B: wave handles 4 pillars, lane = channel; W regs reused across pillars
    const int wv = tid >> 6, c = tid & 63;
    const float* w = W + c * 10;
    const float w0 = w[0], w1 = w[1], w2 = w[2], w3 = w[3], w4 = w[4];
    const float w5 = w[5], w6 = w[6], w7 = w[7], w8 = w[8], w9 = w[9];
    const float Aw = w0 + w4 + w7;   // x coefficient
    const float Bw = w1 + w5 + w8;   // y coefficient
    const float Cw = w2 + w6;        // z coefficient
    const float w07 = w0 + w7, w18 = w1 + w8;
    float ssu = 0.f, sq2 = 0.f;
    #pragma unroll
    for (int j = 0; j < 4; ++j) {
        const int pl = wv * 4 + j;
        const int p = p0 + pl;
        if (p < P) {
            float cxo = cx[p] * VXc + X_OFFSET;
            float cyo = cy[p] * VYc + Y_OFFSET;
            float mx = pinfo[pl][0], my = pinfo[pl][1], mz = pinfo[pl][2];
            int npv = (int)pinfo[pl][3];
            float E = -cxo * w07 - cyo * w18 - mx * w4 - my * w5 - mz * w6 + Z_CONST * w9;
            float smax = -1e30f, smin = 1e30f;
            #pragma unroll
            for (int n = 0; n < NPTS; ++n) {
                float4 pt = pts[pl][n];       // wave-uniform addr -> LDS broadcast
                float v = E;
                v = fmaf(pt.x, Aw, v);
                v = fmaf(pt.y, Bw, v);
                v = fmaf(pt.z, Cw, v);
                v = fmaf(pt.w, w3, v);
                v = (n < npv) ? v : 0.0f;     // masked points -> exactly 0 (matches ref)
                smax = fmaxf(smax, v);
                smin = fminf(smin, v);
                ssu += v;
                sq2 = fmaf(v, v, sq2);
            }
            vmax[(size_t)p * NC + c] = smax;
            vmin[(size_t)p * NC + c] = smin;
        }
    }
    ssum[wv][c] = ssu;
    ssq[wv][c]  = sq2;
    __syncthreads();
    if (tid < NC) {
        float s = ssum[0][tid] + ssum[1][tid] + ssum[2][tid] + ssum[3][tid];
        float q = ssq[0][tid]  + ssq[1][tid]  + ssq[2][tid]  + ssq[3][tid];
        int slot = blockIdx.x & (NSLOTS - 1);
        atomicAdd(&dsum[slot * NC + tid], (double)s);
        atomicAdd(&dsq[slot * NC + tid],  (double)q);
    }
}

// Kernel B: fold slot accumulators -> BN (scale, shift) float2 per channel
__global__ void bn_params_kernel(const double* __restrict__ dsum,
                                 const double* __restrict__ dsq,
                                 const float* __restrict__ gamma,
                                 const float* __restrict__ beta,
                                 float2* __restrict__ st, int P)
{
    int c = threadIdx.x;
    if (c < NC) {
        double s = 0.0, q = 0.0;
        for (int i = 0; i < NSLOTS; ++i) { s += dsum[i * NC + c]; q += dsq[i * NC + c]; }
        double cnt = (double)P * NPTS;
        double mu = s / cnt;
        double var = q / cnt - mu * mu;
        float scale = gamma[c] * (float)(1.0 / sqrt(var + (double)BN_EPS));
        float shift = beta[c] - (float)mu * scale;
        st[c] = make_float2(scale, shift);
    }
}

// Kernel C: gather-style dense output; float4 nontemporal stores, 4 cells/thread
__global__ __launch_bounds__(256) void scatter_out_kernel(
    const int* __restrict__ map, const float* __restrict__ vmax,
    const float* __restrict__ vmin, const float2* __restrict__ st,
    float* __restrict__ out)
{
    __shared__ float2 sst[NC];
    if (threadIdx.x < NC) sst[threadIdx.x] = st[threadIdx.x];
    __syncthreads();

    const int q4 = blockIdx.x * 256 + threadIdx.x;   // quad of 4 cells, x fastest
    if (q4 >= QCELLS) return;
    const int b = blockIdx.y;
    const int4 m = ((const int4*)(map + (size_t)b * CELLS))[q4];
    floatx4* ob = (floatx4*)(out + (size_t)b * NC * CELLS) + q4;
    #pragma unroll 4
    for (int c = 0; c < NC; ++c) {
        float2 s = sst[c];                            // LDS broadcast
        const float* vs = (s.x >= 0.0f) ? vmax : vmin; // wave-uniform select
        floatx4 r = (floatx4)(0.f);
        if (m.x >= 0) r.x = fmaxf(fmaf(s.x, vs[(size_t)m.x * NC + c], s.y), 0.f);
        if (m.y >= 0) r.y = fmaxf(fmaf(s.x, vs[(size_t)m.y * NC + c], s.y), 0.f);
        if (m.z >= 0) r.z = fmaxf(fmaf(s.x, vs[(size_t)m.z * NC + c], s.y), 0.f);
        if (m.w >= 0) r.w = fmaxf(fmaf(s.x, vs[(size_t)m.w * NC + c], s.y), 0.f);
        __builtin_nontemporal_store(r, &ob[(size_t)c * QCELLS]);
    }
}

extern "C" void kernel_launch(void* const* d_in, const int* in_sizes, int n_in,
                              void* d_out, int out_size, void* d_ws, size_t ws_size,
                              hipStream_t stream) {
    const float* pillars = (const float*)d_in[0];
    const float* W       = (const float*)d_in[1];
    const float* gamma   = (const float*)d_in[2];
    const float* beta    = (const float*)d_in[3];
    const int*   cx      = (const int*)d_in[4];
    const int*   cy      = (const int*)d_in[5];
    const int*   cb      = (const int*)d_in[6];
    const int*   np      = (const int*)d_in[7];
    const int P = in_sizes[4];      // 48000

    // workspace carve-up (~28 MB)
    char* ws = (char*)d_ws;
    float* vmax = (float*)ws;
    float* vmin = vmax + (size_t)P * NC;
    int*   map  = (int*)(vmin + (size_t)P * NC);
    size_t mapN = (size_t)NB * CELLS;
    double* dsum = (double*)(((uintptr_t)(map + mapN) + 255) & ~(uintptr_t)255);
    double* dsq  = dsum + NSLOTS * NC;
    float2* st   = (float2*)(dsq + NSLOTS * NC);

    (void)hipMemsetAsync(map, 0xFF, mapN * sizeof(int), stream);           // -1 = empty
    (void)hipMemsetAsync(dsum, 0, (size_t)NSLOTS * NC * 2 * sizeof(double), stream);

    pillar_stats_kernel<<<(P + PPB - 1) / PPB, 256, 0, stream>>>(
        pillars, W, cx, cy, cb, np, vmax, vmin, map, dsum, dsq, P);
    bn_params_kernel<<<1, 64, 0, stream>>>(dsum, dsq, gamma, beta, st, P);
    scatter_out_kernel<<<dim3((QCELLS + 255) / 256, NB), 256, 0, stream>>>(
        map, vmax, vmin, st, (float*)d_out);
}

// Round 4
// 287.550 us; speedup vs baseline: 1.0034x; 1.0034x over previous
//
#include <hip/hip_runtime.h>
#include <stdint.h>

// PointPillars constants (KITTI config)
#define GRID_X 432
#define GRID_Y 496
#define NB 4
#define NPTS 32
#define NC 64
#define NSLOTS 64
#define CELLS (GRID_Y * GRID_X)   // 214272 per batch (y-major, x fastest)
#define QCELLS (CELLS / 4)        // 53568 quads of 4 cells per (b, channel) plane

constexpr float VXc = 0.16f, VYc = 0.16f;
constexpr float X_OFFSET = 0.08f, Y_OFFSET = -39.60f, Z_CONST = -1.0f;
constexpr float BN_EPS = 1e-3f;

typedef float floatx4 __attribute__((ext_vector_type(4)));  // native vec for nontemporal

#define PPB 16   // pillars per block in stats kernel

// Kernel A: per-pillar per-channel max/min + BN stat partials + inverse map.
// map[b][cell] = local_pillar_id + 1 (ushort), 0 = empty -> single memset(0) clears it.
__global__ __launch_bounds__(256) void pillar_stats_kernel(
    const float* __restrict__ pillars, const float* __restrict__ W,
    const int* __restrict__ cx, const int* __restrict__ cy,
    const int* __restrict__ cb, const int* __restrict__ npoints,
    float* __restrict__ vmax, float* __restrict__ vmin, unsigned short* __restrict__ map,
    double* __restrict__ dsum, double* __restrict__ dsq, int P, int ppb)
{
    __shared__ float4 pts[PPB][NPTS];    // 8 KB
    __shared__ float pinfo[PPB][4];      // mx, my, mz, npf
    __shared__ float ssum[4][NC], ssq[4][NC];

    const int tid = threadIdx.x;
    const int p0 = blockIdx.x * PPB;

    // Phase A: stage points + per-pillar xyz centroid (8 pillars per pass, 2 passes)
    #pragma unroll
    for (int pass = 0; pass < 2; ++pass) {
        int pl = (tid >> 5) + pass * 8;
        int n  = tid & 31;
        int p  = p0 + pl;
        float4 v = make_float4(0.f, 0.f, 0.f, 0.f);
        if (p < P) v = ((const float4*)pillars)[(size_t)p * NPTS + n];
        pts[pl][n] = v;
        float sx = v.x, sy = v.y, sz = v.z;
        #pragma unroll
        for (int m = 16; m >= 1; m >>= 1) {
            sx += __shfl_xor(sx, m, 32);
            sy += __shfl_xor(sy, m, 32);
            sz += __shfl_xor(sz, m, 32);
        }
        if (n == 0 && p < P) {
            float npf = (float)npoints[p];
            pinfo[pl][0] = sx / npf;
            pinfo[pl][1] = sy / npf;
            pinfo[pl][2] = sz / npf;
            pinfo[pl][3] = npf;
        }
    }
    // inverse map: cell -> local pillar id + 1 (cells unique per batch by construction)
    if (tid < PPB) {
        int p = p0 + tid;
        if (p < P) {
            int b = cb[p];
            map[(size_t)b * CELLS + (size_t)cy[p] * GRID_X + cx[p]] =
                (unsigned short)(p - b * ppb + 1);
        }
    }
    __syncthreads();

    // Phase B: wave handles 4 pillars, lane = channel; W regs reused across pillars
    const int wv = tid >> 6, c = tid & 63;
    const float* w = W + c * 10;
    const float w0 = w[0], w1 = w[1], w2 = w[2], w3 = w[3], w4 = w[4];
    const float w5 = w[5], w6 = w[6], w7 = w[7], w8 = w[8], w9 = w[9];
    const float Aw = w0 + w4 + w7;   // x coefficient
    const float Bw = w1 + w5 + w8;   // y coefficient
    const float Cw = w2 + w6;        // z coefficient
    const float w07 = w0 + w7, w18 = w1 + w8;
    float ssu = 0.f, sq2 = 0.f;
    #pragma unroll
    for (int j = 0; j < 4; ++j) {
        const int pl = wv * 4 + j;
        const int p = p0 + pl;
        if (p < P) {
            float cxo = cx[p] * VXc + X_OFFSET;
            float cyo = cy[p] * VYc + Y_OFFSET;
            float mx = pinfo[pl][0], my = pinfo[pl][1], mz = pinfo[pl][2];
            int npv = (int)pinfo[pl][3];
            float E = -cxo * w07 - cyo * w18 - mx * w4 - my * w5 - mz * w6 + Z_CONST * w9;
            float smax = -1e30f, smin = 1e30f;
            #pragma unroll
            for (int n = 0; n < NPTS; ++n) {
                float4 pt = pts[pl][n];       // wave-uniform addr -> LDS broadcast
                float v = E;
                v = fmaf(pt.x, Aw, v);
                v = fmaf(pt.y, Bw, v);
                v = fmaf(pt.z, Cw, v);
                v = fmaf(pt.w, w3, v);
                v = (n < npv) ? v : 0.0f;     // masked points -> exactly 0 (matches ref)
                smax = fmaxf(smax, v);
                smin = fminf(smin, v);
                ssu += v;
                sq2 = fmaf(v, v, sq2);
            }
            vmax[(size_t)p * NC + c] = smax;
            vmin[(size_t)p * NC + c] = smin;
        }
    }
    ssum[wv][c] = ssu;
    ssq[wv][c]  = sq2;
    __syncthreads();
    if (tid < NC) {
        float s = ssum[0][tid] + ssum[1][tid] + ssum[2][tid] + ssum[3][tid];
        float q = ssq[0][tid]  + ssq[1][tid]  + ssq[2][tid]  + ssq[3][tid];
        int slot = blockIdx.x & (NSLOTS - 1);
        atomicAdd(&dsum[slot * NC + tid], (double)s);
        atomicAdd(&dsq[slot * NC + tid],  (double)q);
    }
}

// Kernel B: fold slot accumulators -> BN (scale, shift) float2 per channel
__global__ void bn_params_kernel(const double* __restrict__ dsum,
                                 const double* __restrict__ dsq,
                                 const float* __restrict__ gamma,
                                 const float* __restrict__ beta,
                                 float2* __restrict__ st, int P)
{
    int c = threadIdx.x;
    if (c < NC) {
        double s = 0.0, q = 0.0;
        for (int i = 0; i < NSLOTS; ++i) { s += dsum[i * NC + c]; q += dsq[i * NC + c]; }
        double cnt = (double)P * NPTS;
        double mu = s / cnt;
        double var = q / cnt - mu * mu;
        float scale = gamma[c] * (float)(1.0 / sqrt(var + (double)BN_EPS));
        float shift = beta[c] - (float)mu * scale;
        st[c] = make_float2(scale, shift);
    }
}

// Kernel C: gather-style dense output; float4 nontemporal stores, 4 cells/thread
__global__ __launch_bounds__(256) void scatter_out_kernel(
    const unsigned short* __restrict__ map, const float* __restrict__ vmax,
    const float* __restrict__ vmin, const float2* __restrict__ st,
    float* __restrict__ out, int ppb)
{
    __shared__ float2 sst[NC];
    if (threadIdx.x < NC) sst[threadIdx.x] = st[threadIdx.x];
    __syncthreads();

    const int q4 = blockIdx.x * 256 + threadIdx.x;   // quad of 4 cells, x fastest
    if (q4 >= QCELLS) return;
    const int b = blockIdx.y;
    const ushort4 m = ((const ushort4*)(map + (size_t)b * CELLS))[q4];
    const size_t pbase = (size_t)b * ppb;
    floatx4* ob = (floatx4*)(out + (size_t)b * NC * CELLS) + q4;
    #pragma unroll 4
    for (int c = 0; c < NC; ++c) {
        float2 s = sst[c];                                 // LDS broadcast
        const float* vs = ((s.x >= 0.0f) ? vmax : vmin)    // wave-uniform select
                          + pbase * NC + c;
        floatx4 r = (floatx4)(0.f);
        if (m.x) r.x = fmaxf(fmaf(s.x, vs[((int)m.x - 1) * NC], s.y), 0.f);
        if (m.y) r.y = fmaxf(fmaf(s.x, vs[((int)m.y - 1) * NC], s.y), 0.f);
        if (m.z) r.z = fmaxf(fmaf(s.x, vs[((int)m.z - 1) * NC], s.y), 0.f);
        if (m.w) r.w = fmaxf(fmaf(s.x, vs[((int)m.w - 1) * NC], s.y), 0.f);
        __builtin_nontemporal_store(r, &ob[(size_t)c * QCELLS]);
    }
}

extern "C" void kernel_launch(void* const* d_in, const int* in_sizes, int n_in,
                              void* d_out, int out_size, void* d_ws, size_t ws_size,
                              hipStream_t stream) {
    const float* pillars = (const float*)d_in[0];
    const float* W       = (const float*)d_in[1];
    const float* gamma   = (const float*)d_in[2];
    const float* beta    = (const float*)d_in[3];
    const int*   cx      = (const int*)d_in[4];
    const int*   cy      = (const int*)d_in[5];
    const int*   cb      = (const int*)d_in[6];
    const int*   np      = (const int*)d_in[7];
    const int P = in_sizes[4];      // 48000
    const int ppb = P / NB;         // 12000 pillars per batch (fits ushort with +1)

    // workspace carve-up: [map ushort | dsum | dsq | st | vmax | vmin]
    // map bytes = 4*214272*2 = 1,714,176 (divisible by 256) -> dsum aligned.
    char* ws = (char*)d_ws;
    unsigned short* map = (unsigned short*)ws;
    size_t mapBytes = (size_t)NB * CELLS * sizeof(unsigned short);
    double* dsum = (double*)(ws + mapBytes);
    double* dsq  = dsum + NSLOTS * NC;
    float2* st   = (float2*)(dsq + NSLOTS * NC);
    float* vmax  = (float*)(st + NC);
    float* vmin  = vmax + (size_t)P * NC;

    // single clear: map sentinel (0) + dsum/dsq zeros
    size_t clearBytes = mapBytes + (size_t)NSLOTS * NC * 2 * sizeof(double);
    (void)hipMemsetAsync(ws, 0, clearBytes, stream);

    pillar_stats_kernel<<<(P + PPB - 1) / PPB, 256, 0, stream>>>(
        pillars, W, cx, cy, cb, np, vmax, vmin, map, dsum, dsq, P, ppb);
    bn_params_kernel<<<1, 64, 0, stream>>>(dsum, dsq, gamma, beta, st, P);
    scatter_out_kernel<<<dim3((QCELLS + 255) / 256, NB), 256, 0, stream>>>(
        map, vmax, vmin, st, (float*)d_out, ppb);
}